// Round 1
// baseline (338.142 us; speedup 1.0000x reference)
//
#include <hip/hip_runtime.h>
#include <cstdint>
#include <cstddef>

#define BB 8
#define LL 512
#define HH 20
#define DD 1280
#define KK 32

__device__ __forceinline__ float block_sum256(float v, float* red) {
    #pragma unroll
    for (int off = 32; off; off >>= 1) v += __shfl_down(v, off);
    int wid = threadIdx.x >> 6;
    if ((threadIdx.x & 63) == 0) red[wid] = v;
    __syncthreads();
    if (threadIdx.x == 0) red[0] = red[0] + red[1] + red[2] + red[3];
    __syncthreads();
    return red[0];
}

// Kernel A: per output-row e, fold classifier+contrast vectors through the
// weight matrices:  w1[e]=sum_d cls_W[e,d]*cls_c1[d]*clsclf_W[d], etc.
// Layout in ws: [w1 | w2 | v1 | v2], each DD floats.
__global__ __launch_bounds__(256) void k_weights(
    const float* __restrict__ cls_W, const float* __restrict__ env_W,
    const float* __restrict__ clsclf_W, const float* __restrict__ envclf_W,
    const float* __restrict__ cls_c1, const float* __restrict__ cls_c2,
    const float* __restrict__ env_c1, const float* __restrict__ env_c2,
    float* __restrict__ ws)
{
    int e = blockIdx.x;
    const float* crow = cls_W + (size_t)e * DD;
    const float* erow = env_W + (size_t)e * DD;
    float s1 = 0.f, s2 = 0.f, s3 = 0.f, s4 = 0.f;
    for (int d = threadIdx.x; d < DD; d += 256) {
        float cw = crow[d], ew = erow[d];
        float cc = clsclf_W[d], ec = envclf_W[d];
        s1 = fmaf(cw * cls_c1[d], cc, s1);
        s2 = fmaf(cw * cls_c2[d], cc, s2);
        s3 = fmaf(ew * env_c1[d], ec, s3);
        s4 = fmaf(ew * env_c2[d], ec, s4);
    }
    __shared__ float red[4][4];
    #pragma unroll
    for (int off = 32; off; off >>= 1) {
        s1 += __shfl_down(s1, off);
        s2 += __shfl_down(s2, off);
        s3 += __shfl_down(s3, off);
        s4 += __shfl_down(s4, off);
    }
    if ((threadIdx.x & 63) == 0) {
        int w = threadIdx.x >> 6;
        red[w][0] = s1; red[w][1] = s2; red[w][2] = s3; red[w][3] = s4;
    }
    __syncthreads();
    if (threadIdx.x < 4) {
        float s = red[0][threadIdx.x] + red[1][threadIdx.x]
                + red[2][threadIdx.x] + red[3][threadIdx.x];
        ws[(size_t)threadIdx.x * DD + e] = s;
    }
}

// Kernel B: one block per (b, rep). Computes head-summed attention scores at
// row pos[b], wave-level top-K (tie -> lowest index, matching lax.top_k),
// gathers+sums the K selected rep rows, and emits
//   partials[2b+r] = <rep[b,0,:], w_r> + <mean_k rep[b,idx_k,:], v_r>.
__global__ __launch_bounds__(256) void k_branch(
    const float* __restrict__ rep1, const float* __restrict__ rep2,
    const float* __restrict__ attn1, const float* __restrict__ attn2,
    const int* __restrict__ pos, const float* __restrict__ ws,
    float* __restrict__ partials)
{
    int r = blockIdx.x & 1;
    int b = blockIdx.x >> 1;
    const float* rep  = r ? rep2  : rep1;
    const float* attn = r ? attn2 : attn1;
    const float* wcls = ws + (size_t)r * DD;
    const float* venv = ws + (size_t)(2 + r) * DD;
    int p = pos[b];

    __shared__ float score[LL];
    __shared__ int sidx[KK];
    __shared__ float red[4];

    // scores: sum over H heads of attn[b,h,p,l]  (mean/H is rank-invariant)
    const float* arow = attn + (((size_t)b * HH) * LL + (size_t)p) * LL;
    for (int l = threadIdx.x; l < LL; l += 256) {
        float s = 0.f;
        #pragma unroll
        for (int h = 0; h < HH; ++h) s += arow[(size_t)h * LL * LL + l];
        score[l] = s;
    }
    __syncthreads();

    // top-K via 32x wave argmax on wave 0; values live in registers.
    if (threadIdx.x < 64) {
        int lane = threadIdx.x;
        float sv[LL / 64];
        #pragma unroll
        for (int j = 0; j < LL / 64; ++j) sv[j] = score[lane + 64 * j];
        for (int k = 0; k < KK; ++k) {
            unsigned long long best = 0ull;
            #pragma unroll
            for (int j = 0; j < LL / 64; ++j) {
                float s = sv[j];
                int l = lane + 64 * j;
                // scores are sums of uniforms >= 0, so float bits are monotone;
                // (LL-1-l) in low word makes ties pick the smaller index.
                unsigned long long key = (s < 0.f) ? 0ull
                    : (((unsigned long long)__float_as_uint(s)) << 32)
                      | (unsigned)(LL - 1 - l);
                best = best > key ? best : key;
            }
            #pragma unroll
            for (int off = 32; off; off >>= 1) {
                unsigned long long o = __shfl_xor(best, off);
                best = best > o ? best : o;
            }
            int widx = (LL - 1) - (int)(best & 0xffffffffu);
            if (lane == 0) sidx[k] = widx;
            if ((widx & 63) == lane) sv[widx >> 6] = -1.f;  // remove winner
        }
    }
    __syncthreads();

    const float* repb = rep + (size_t)b * LL * DD;
    float acc[DD / 256];
    #pragma unroll
    for (int j = 0; j < DD / 256; ++j) acc[j] = 0.f;
    for (int k = 0; k < KK; ++k) {
        const float* row = repb + (size_t)sidx[k] * DD;
        #pragma unroll
        for (int j = 0; j < DD / 256; ++j) acc[j] += row[threadIdx.x + 256 * j];
    }
    float partial = 0.f;
    #pragma unroll
    for (int j = 0; j < DD / 256; ++j) {
        int e = threadIdx.x + 256 * j;
        partial = fmaf(repb[e], wcls[e], partial);                 // CLS token dot
        partial = fmaf(acc[j] * (1.0f / KK), venv[e], partial);    // env mean dot
    }
    float tot = block_sum256(partial, red);
    if (threadIdx.x == 0) partials[blockIdx.x] = tot;
}

// Kernel C: bias constants + combine.
__global__ __launch_bounds__(256) void k_final(
    const float* __restrict__ cls_b, const float* __restrict__ env_b,
    const float* __restrict__ clsclf_W, const float* __restrict__ envclf_W,
    const float* __restrict__ clsclf_b, const float* __restrict__ envclf_b,
    const float* __restrict__ cls_c1, const float* __restrict__ cls_c2,
    const float* __restrict__ env_c1, const float* __restrict__ env_c2,
    const float* __restrict__ partials, float* __restrict__ out)
{
    __shared__ float red[4];
    float p = 0.f;
    for (int d = threadIdx.x; d < DD; d += 256) {
        p += cls_b[d] * (cls_c1[d] + cls_c2[d]) * clsclf_W[d]
           + env_b[d] * (env_c1[d] + env_c2[d]) * envclf_W[d];
    }
    float tot = block_sum256(p, red);
    if (threadIdx.x < BB) {
        float c = tot + clsclf_b[0] + envclf_b[0];
        out[threadIdx.x] = 0.5f * (partials[2 * threadIdx.x]
                                 + partials[2 * threadIdx.x + 1] + c);
    }
}

extern "C" void kernel_launch(void* const* d_in, const int* in_sizes, int n_in,
                              void* d_out, int out_size, void* d_ws, size_t ws_size,
                              hipStream_t stream) {
    const float* rep1     = (const float*)d_in[0];
    const float* rep2     = (const float*)d_in[1];
    const float* attn1    = (const float*)d_in[2];
    const float* attn2    = (const float*)d_in[3];
    const int*   pos      = (const int*)d_in[4];
    const float* cls_W    = (const float*)d_in[5];
    const float* cls_b    = (const float*)d_in[6];
    const float* env_W    = (const float*)d_in[7];
    const float* env_b    = (const float*)d_in[8];
    const float* clsclf_W = (const float*)d_in[9];
    const float* clsclf_b = (const float*)d_in[10];
    const float* envclf_W = (const float*)d_in[11];
    const float* envclf_b = (const float*)d_in[12];
    const float* cls_c1   = (const float*)d_in[13];
    const float* cls_c2   = (const float*)d_in[14];
    const float* env_c1   = (const float*)d_in[15];
    const float* env_c2   = (const float*)d_in[16];

    float* ws = (float*)d_ws;           // [w1|w2|v1|v2] = 4*DD floats
    float* partials = ws + 4 * DD;      // 16 floats
    float* out = (float*)d_out;         // 8 floats

    k_weights<<<DD, 256, 0, stream>>>(cls_W, env_W, clsclf_W, envclf_W,
                                      cls_c1, cls_c2, env_c1, env_c2, ws);
    k_branch<<<2 * BB, 256, 0, stream>>>(rep1, rep2, attn1, attn2, pos, ws,
                                         partials);
    k_final<<<1, 256, 0, stream>>>(cls_b, env_b, clsclf_W, envclf_W,
                                   clsclf_b, envclf_b, cls_c1, cls_c2,
                                   env_c1, env_c2, partials, out);
}